// Round 23
// baseline (220.171 us; speedup 1.0000x reference)
//
#include <hip/hip_runtime.h>
#include <hip/hip_bf16.h>
#include <math.h>

// Problem constants
#define PTOT 36864          // Bsz*Hs*Ws = 16*48*48
#define DIM 768
#define NCOLS 640           // packed projection columns (613 used, padded)
#define IMG 2304            // 48*48
#define KSTEPS 24           // 768/32
#define NPBLK 288           // PTOT/128

typedef unsigned short ushort_t;
typedef unsigned int uint_t;
typedef __attribute__((ext_vector_type(8))) short bfx8;
typedef __attribute__((ext_vector_type(4))) float f32x4;

#define MFMA_BF16(a, b, c) __builtin_amdgcn_mfma_f32_16x16x32_bf16((a), (b), (c), 0, 0, 0)

// barrier that does NOT drain vmcnt (glds completion is enforced per-wave via
// register dependencies BEFORE reaching this) — only ds ops + barrier.
#define LGKM_BARRIER() do {                               \
    asm volatile("s_waitcnt lgkmcnt(0)" ::: "memory");    \
    __builtin_amdgcn_s_barrier();                         \
    __builtin_amdgcn_sched_barrier(0);                    \
  } while (0)

__device__ __forceinline__ float sigmoidf_(float v) { return 1.f / (1.f + __expf(-v)); }
__device__ __forceinline__ float siluf_(float v)    { return v   / (1.f + __expf(-v)); }
__device__ __forceinline__ float rfl(float v) {
  return __int_as_float(__builtin_amdgcn_readfirstlane(__float_as_int(v)));
}
__device__ __forceinline__ float bf2f(ushort_t h) {
  return __uint_as_float(((uint_t)h) << 16);
}

// async global->LDS, 16B per lane; LDS dest = wave-uniform base + lane*16
typedef __attribute__((address_space(3))) unsigned int lds_uint;
typedef __attribute__((address_space(1))) const unsigned int g_uint;
__device__ __forceinline__ void glds16(const void* gsrc, void* ldst) {
  __builtin_amdgcn_global_load_lds((g_uint*)gsrc, (lds_uint*)ldst, 16, 0, 0);
}

// split a pair of f32 into packed bf16 hi word + bf16 lo word (cvt_pk-based)
__device__ __forceinline__ void split2(float a, float b, uint_t& hw, uint_t& lw) {
  __hip_bfloat162 hh = __float22bfloat162_rn(make_float2(a, b));
  uint_t hu; __builtin_memcpy(&hu, &hh, 4);
  float ha = __uint_as_float(hu << 16);
  float hb = __uint_as_float(hu & 0xffff0000u);
  __hip_bfloat162 ll = __float22bfloat162_rn(make_float2(a - ha, b - hb));
  uint_t lu; __builtin_memcpy(&lu, &ll, 4);
  hw = hu; lw = lu;
}
__device__ __forceinline__ uint_t cvt2_hi(float a, float b) {
  __hip_bfloat162 hh = __float22bfloat162_rn(make_float2(a, b));
  uint_t hu; __builtin_memcpy(&hu, &hh, 4);
  return hu;
}
__device__ __forceinline__ ushort_t f2bf(float a) {
  return (ushort_t)(cvt2_hi(a, 0.f) & 0xffffu);
}
__device__ __forceinline__ void split8_fast(const float* f, uint4& hi, uint4& lo) {
  uint_t* Hp = (uint_t*)&hi;
  uint_t* Lp = (uint_t*)&lo;
#pragma unroll
  for (int q = 0; q < 4; ++q) split2(f[2 * q], f[2 * q + 1], Hp[q], Lp[q]);
}
__device__ __forceinline__ void cvt8_hi(const float* f, uint4& hi) {
  uint_t* Hp = (uint_t*)&hi;
#pragma unroll
  for (int q = 0; q < 4; ++q) Hp[q] = cvt2_hi(f[2 * q], f[2 * q + 1]);
}

// ---------------------------------------------------------------------------
// pack: projection weights -> split-bf16 [c][k]; W_out^T -> plain bf16 [j][k];
// fused bias.
// ---------------------------------------------------------------------------
__global__ void pack_kernel(
    const float* __restrict__ W_B, const float* __restrict__ W_C,
    const float* __restrict__ W_dec, const float* __restrict__ W_th,
    const float* __restrict__ W_X, const float* __restrict__ W_lam,
    const float* __restrict__ b_B, const float* __restrict__ b_C,
    const float* __restrict__ b_dec, const float* __restrict__ b_th,
    const float* __restrict__ b_X, const float* __restrict__ b_lam,
    const float* __restrict__ B_bias, const float* __restrict__ C_bias,
    const float* __restrict__ W_out,
    ushort_t* __restrict__ WhiT, ushort_t* __restrict__ WloT,
    ushort_t* __restrict__ WoT, float* __restrict__ bias_all) {
  int idx = blockIdx.x * 256 + threadIdx.x;
  const int NW = NCOLS * DIM;          // 491520
  const int NWO = DIM * 256;           // 196608
  if (idx < NW) {
    int c = idx / DIM, k = idx - c * DIM;
    float v;
    if      (c < 256) v = W_B[k * 256 + c];
    else if (c < 512) v = W_C[k * 256 + (c - 256)];
    else if (c < 576) v = W_dec[k * 64 + (c - 512)];
    else if (c < 608) v = W_th[k * 32 + (c - 576)];
    else if (c < 612) v = W_X[k * 4 + (c - 608)];
    else if (c == 612) v = W_lam[k];
    else v = 0.f;
    uint_t hw, lw;
    split2(v, 0.f, hw, lw);
    WhiT[idx] = (ushort_t)(hw & 0xffffu);
    WloT[idx] = (ushort_t)(lw & 0xffffu);
  } else if (idx < NW + NWO) {
    int t = idx - NW;
    int j = t / 256, k = t - j * 256;
    WoT[t] = f2bf(W_out[k * DIM + j]);
  }
  if (idx < NCOLS) {
    int c = idx;
    float v;
    if      (c < 256) v = b_B[c] + B_bias[c];
    else if (c < 512) v = b_C[c - 256] + C_bias[c - 256];
    else if (c < 576) v = b_dec[c - 512];
    else if (c < 608) v = b_th[c - 576];
    else if (c < 612) v = b_X[c - 608];
    else if (c == 612) v = b_lam[0];
    else v = 0.f;
    bias_all[c] = v;
  }
}

// ---------------------------------------------------------------------------
// FUSED projection GEMM: one dispatch, 1440 blocks of 512 threads.
//   blocks [0,1152): LIGHT path (c 0-511, B/C), BK=64, async schedule:
//     W TRIPLE-buffered glds (staged 2 phases ahead); x reg-staged bf16
//     double-buffered. Barriers are lgkm-only (glds completion enforced via
//     writeX register waits one phase early). T5 setprio around MFMA.
//   blocks [1152,1440): HEAVY path (c 512-612), BK=32 (r12 structure,
//     __syncthreads): W hi+lo glds + x f32 glds, split-bf16 3-MFMA.
// LDS: light 3*16 + 2*16 = 80 KB; heavy 2*32 = 64 KB; union 80 KB -> 2/CU.
// ---------------------------------------------------------------------------
__global__ __launch_bounds__(512, 4) void gemm_proj_fused(
    const float* __restrict__ x, const ushort_t* __restrict__ WhiT,
    const ushort_t* __restrict__ WloT, const float* __restrict__ biasall,
    ushort_t* __restrict__ projBC, float* __restrict__ projS) {
  __shared__ ushort_t S[40960];   // 80 KB union
  const int tid = threadIdx.x;
  const int lane = tid & 63, wv = tid >> 6;   // 8 waves
  const int wr = wv >> 2, wc = wv & 3;        // 64c x 32p per wave
  const int lk = lane >> 4, lm = lane & 15;

  f32x4 acc[4][2];
#pragma unroll
  for (int i = 0; i < 4; ++i)
#pragma unroll
    for (int j = 0; j < 2; ++j) acc[i][j] = (f32x4)0.f;

  if (blockIdx.x < 1152) {
    // ------------------- LIGHT PATH (BK = 64, async) --------------------
    int lin = blockIdx.x;                  // 0..1151, 1152 = 8*144
    int id2 = (lin & 7) * 144 + (lin >> 3);
    const int cblk = id2 & 3, pblk = id2 >> 2;
    const int c0 = cblk * 128, p0 = pblk * 128;

    const int r0 = tid >> 3,         s0 = tid & 7,         g0 = s0 ^ (r0 & 7);
    const int r1 = (tid + 512) >> 3, s1 = (tid + 512) & 7, g1 = s1 ^ (r1 & 7);
    const float* xsrc0 = x + (size_t)(p0 + r0) * DIM + g0 * 8;
    const float* xsrc1 = x + (size_t)(p0 + r1) * DIM + g1 * 8;

    float4 xr[4];   // 16 VGPR prefetch

    // W buffers: base wb*8192 elems (wb 0..2); X buffers: 24576 + xb*8192.
    auto stageW = [&](int wb, int ph) {
      const int k0 = ph * 64;
#pragma unroll
      for (int j = 0; j < 2; ++j) {
        int mb = __builtin_amdgcn_readfirstlane(j * 512 + wv * 64);
        int m = mb + lane;
        int row = m >> 3, sp = m & 7;
        int g = sp ^ (row & 7);
        glds16(&WhiT[(size_t)(c0 + row) * DIM + k0 + g * 8],
               (void*)&S[wb * 8192 + mb * 8]);
      }
    };
    auto loadX = [&](int ph) {
      const float* q0 = xsrc0 + ph * 64;
      xr[0] = *(const float4*)q0;
      xr[1] = *(const float4*)(q0 + 4);
      const float* q1 = xsrc1 + ph * 64;
      xr[2] = *(const float4*)q1;
      xr[3] = *(const float4*)(q1 + 4);
    };
    auto writeX = [&](int xb) {
      float fv[8];
      uint4 hv;
      *(float4*)&fv[0] = xr[0]; *(float4*)&fv[4] = xr[1];
      cvt8_hi(fv, hv);
      *(uint4*)&S[24576 + xb * 8192 + (size_t)tid * 8] = hv;
      *(float4*)&fv[0] = xr[2]; *(float4*)&fv[4] = xr[3];
      cvt8_hi(fv, hv);
      *(uint4*)&S[24576 + xb * 8192 + (size_t)(tid + 512) * 8] = hv;
    };

    // prologue: issue order matters for the reg-dependency drains.
    stageW(0, 0);       // vmem
    loadX(0);           // vmem (after stageW(0))
    stageW(1, 1);       // vmem (after loadX(0))
    writeX(0);          // waits loadX(0) regs -> drains stageW(0)
    loadX(1);           // for phase 1 (after stageW(1))
    LGKM_BARRIER();     // publish X[0]; W(0) already drained above

    for (int ph = 0; ph < 12; ++ph) {
      const int wb = ph % 3, xb = ph & 1;
      if (ph + 2 < 12) stageW((ph + 2) % 3, ph + 2);
      if (ph + 1 < 12) writeX(xb ^ 1);   // waits loadX(ph+1) -> drains stageW(ph+1)
      if (ph + 2 < 12) loadX(ph + 2);
      __builtin_amdgcn_s_setprio(1);
#pragma unroll
      for (int s = 0; s < 2; ++s) {
        bfx8 ah[4];
#pragma unroll
        for (int f = 0; f < 4; ++f) {
          int row = wr * 64 + f * 16 + lm;
          int slot = (s * 4 + lk) ^ (row & 7);
          ah[f] = *(const bfx8*)&S[wb * 8192 + (row * 8 + slot) * 8];
        }
        bfx8 bh[2];
#pragma unroll
        for (int n = 0; n < 2; ++n) {
          int row = wc * 32 + n * 16 + lm;
          int slot = (s * 4 + lk) ^ (row & 7);
          bh[n] = *(const bfx8*)&S[24576 + xb * 8192 + (row * 8 + slot) * 8];
        }
#pragma unroll
        for (int i = 0; i < 4; ++i)
#pragma unroll
          for (int j = 0; j < 2; ++j)
            acc[i][j] = MFMA_BF16(ah[i], bh[j], acc[i][j]);
      }
      __builtin_amdgcn_s_setprio(0);
      LGKM_BARRIER();   // end of phase: publish writeX(ph+1); W(ph+1) drained
    }

#pragma unroll
    for (int i = 0; i < 4; ++i) {
#pragma unroll
      for (int r = 0; r < 4; ++r) {
        int c = c0 + wr * 64 + i * 16 + lk * 4 + r;
        float bia = biasall[c];
#pragma unroll
        for (int j = 0; j < 2; ++j) {
          float z = siluf_(acc[i][j][r] + bia);
          projBC[(size_t)c * PTOT + p0 + wc * 32 + j * 16 + lm] = f2bf(z);
        }
      }
    }
  } else {
    // ----------------------- HEAVY PATH (r12) ---------------------------
    int lin = blockIdx.x - 1152;           // 0..287, 288 = 8*36
    int id2 = (lin & 7) * 36 + (lin >> 3);
    const int pblk = id2;
    const int c0 = 512, p0 = pblk * 128;

    auto stage = [&](int buf, int kidx) {
      const int k0 = kidx * 32;
      {
        int mb = __builtin_amdgcn_readfirstlane(wv * 64);
        int m = mb + lane;
        int row = m >> 2, sp = m & 3;
        int g = sp ^ ((row >> 1) & 3);
        glds16(&WhiT[(size_t)(c0 + row) * DIM + k0 + g * 8],
               (void*)&S[buf * 16384 + mb * 8]);
      }
      {
        int mb = __builtin_amdgcn_readfirstlane(wv * 64);
        int m = mb + lane;
        int row = m >> 2, sp = m & 3;
        int g = sp ^ ((row >> 1) & 3);
        glds16(&WloT[(size_t)(c0 + row) * DIM + k0 + g * 8],
               (void*)&S[buf * 16384 + 4096 + mb * 8]);
      }
      float* Xf = (float*)&S[buf * 16384 + 8192];
#pragma unroll
      for (int j = 0; j < 2; ++j) {
        int mb = __builtin_amdgcn_readfirstlane(j * 512 + wv * 64);
        int m = mb + lane;
        int row = m >> 3, sp = m & 7;
        int g = sp ^ (row & 7);
        glds16(&x[(size_t)(p0 + row) * DIM + k0 + g * 4],
               (void*)&Xf[mb * 4]);
      }
    };

    stage(0, 0);
    __syncthreads();

    for (int kidx = 0; kidx < KSTEPS; ++kidx) {
      const int cur = kidx & 1;
      if (kidx + 1 < KSTEPS) stage(cur ^ 1, kidx + 1);

      bfx8 ah[4], al[4];
#pragma unroll
      for (int f = 0; f < 4; ++f) {
        int row = wr * 64 + f * 16 + lm;
        int sp = lk ^ ((row >> 1) & 3);
        int idx = (row * 4 + sp) * 8;
        ah[f] = *(const bfx8*)&S[cur * 16384 + idx];
        al[f] = *(const bfx8*)&S[cur * 16384 + 4096 + idx];
      }
      const float* Xf = (const float*)&S[cur * 16384 + 8192];
      bfx8 bh[2], bl[2];
#pragma unroll
      for (int n = 0; n < 2; ++n) {
        int row = wc * 32 + n * 16 + lm;
        int sp0 = (2 * lk)     ^ (row & 7);
        int sp1 = (2 * lk + 1) ^ (row & 7);
        float fv[8];
        *(float4*)&fv[0] = *(const float4*)&Xf[(row * 8 + sp0) * 4];
        *(float4*)&fv[4] = *(const float4*)&Xf[(row * 8 + sp1) * 4];
        uint4 hv, lv;
        split8_fast(fv, hv, lv);
        bh[n] = *(bfx8*)&hv;
        bl[n] = *(bfx8*)&lv;
      }
      __builtin_amdgcn_s_setprio(1);
#pragma unroll
      for (int i = 0; i < 4; ++i)
#pragma unroll
        for (int j = 0; j < 2; ++j) {
          acc[i][j] = MFMA_BF16(ah[i], bh[j], acc[i][j]);
          acc[i][j] = MFMA_BF16(al[i], bh[j], acc[i][j]);
          acc[i][j] = MFMA_BF16(ah[i], bl[j], acc[i][j]);
        }
      __builtin_amdgcn_s_setprio(0);
      __syncthreads();
    }

#pragma unroll
    for (int i = 0; i < 4; ++i) {
#pragma unroll
      for (int r = 0; r < 4; ++r) {
        int c = c0 + wr * 64 + i * 16 + lk * 4 + r;
        if (c >= 613) continue;
        float bia = biasall[c];
        int rowo = c - 512;
        bool do_silu = (c >= 608 && c < 612);
        bool do_sig  = (c < 576) || (c == 612);
#pragma unroll
        for (int j = 0; j < 2; ++j) {
          float z = acc[i][j][r] + bia;
          if (do_silu) z = siluf_(z);
          else if (do_sig) z = sigmoidf_(z);
          projS[(size_t)rowo * PTOT + p0 + wc * 32 + j * 16 + lm] = z;
        }
      }
    }
  }
}

// ---------------------------------------------------------------------------
// Iteration kernel: one block per (n-pair, r, batch), 12 iterations fused.
// ---------------------------------------------------------------------------
__global__ __launch_bounds__(256) void iter_kernel(
    const ushort_t* __restrict__ projBC, const float* __restrict__ projS,
    const float* __restrict__ conv_w, const float* __restrict__ conv_b,
    ushort_t* __restrict__ HgBf) {
  const int n2 = blockIdx.x;   // channel pair 0..31
  const int r  = blockIdx.y;   // 0..3
  const int b  = blockIdx.z;   // 0..15
  const int n0 = 2 * n2, n1 = n0 + 1;
  const int tid = threadIdx.x;
  const int bh = tid >> 4, bw = tid & 15;   // 3x3 strip coords
  const int pbase = b * IMG;

  __shared__ float2 HS[2][50 * 51];   // [buf][(h+1)*51 + (w+1)], zero halo

  float w0[9], w1[9];
#pragma unroll
  for (int t = 0; t < 9; ++t) {
    w0[t] = rfl(conv_w[t * 64 + n0]);
    w1[t] = rfl(conv_w[t * 64 + n1]);
  }
  const float cvb0 = rfl(conv_b[n0]), cvb1 = rfl(conv_b[n1]);

  {
    float4 zz = {0.f, 0.f, 0.f, 0.f};
    float4* z = (float4*)&HS[0][0];
#pragma unroll
    for (int u = 0; u < 10; ++u) {
      int q = tid + 256 * u;
      if (q < 2550) z[q] = zz;
    }
  }

  const ushort_t* rowB0 = projBC + (size_t)(n0 * 4 + r) * PTOT + pbase;
  const ushort_t* rowB1 = projBC + (size_t)(n1 * 4 + r) * PTOT + pbase;
  const ushort_t* rowC0 = projBC + (size_t)(256 + n0 * 4 + r) * PTOT + pbase;
  const ushort_t* rowC1 = projBC + (size_t)(256 + n1 * 4 + r) * PTOT + pbase;
  const float* rowA0 = projS + (size_t)n0 * PTOT + pbase;          // alpha
  const float* rowA1 = projS + (size_t)n1 * PTOT + pbase;
  const float* rowTh = projS + (size_t)(64 + n2) * PTOT + pbase;   // theta
  const float* rowXv = projS + (size_t)(96 + r) * PTOT + pbase;    // X
  const float* rowGm = projS + (size_t)100 * PTOT + pbase;         // gamma

  float be0[9], be1[9], cb[9], sb[9], al0[9], al1[9], gmv[9];
#pragma unroll
  for (int s = 0; s < 9; ++s) {
    int dy = s / 3, dx = s - 3 * dy;
    int i = (3 * bh + dy) * 48 + 3 * bw + dx;
    float sn, cn;
    __sincosf(rowTh[i], &sn, &cn);
    cb[s] = cn; sb[s] = sn;
    float B0 = bf2f(rowB0[i]), B1 = bf2f(rowB1[i]), X = rowXv[i];
    be0[s] = (B0 * cn - B1 * sn) * X;   // inj at angle theta (iteration 0)
    be1[s] = (B0 * sn + B1 * cn) * X;
    al0[s] = rowA0[i]; al1[s] = rowA1[i];
    gmv[s] = rowGm[i];
  }
  __syncthreads();

  int cur = 0;
  for (int it = 0; it < 12; ++it) {
    float a0[9], a1[9];
#pragma unroll
    for (int s = 0; s < 9; ++s) { a0[s] = cvb0; a1[s] = cvb1; }
#pragma unroll
    for (int yy = 0; yy < 5; ++yy) {
      float2 row[5];
#pragma unroll
      for (int xx = 0; xx < 5; ++xx)
        row[xx] = HS[cur][(3 * bh + yy) * 51 + 3 * bw + xx];
#pragma unroll
      for (int dy = 0; dy < 3; ++dy) {
        int ty = yy - dy;
        if (ty < 0 || ty > 2) continue;
#pragma unroll
        for (int dx = 0; dx < 3; ++dx)
#pragma unroll
          for (int tx = 0; tx < 3; ++tx) {
            a0[dy * 3 + dx] += row[dx + tx].x * w0[ty * 3 + tx];
            a1[dy * 3 + dx] += row[dx + tx].y * w1[ty * 3 + tx];
          }
      }
    }
#pragma unroll
    for (int s = 0; s < 9; ++s) {
      int dy = s / 3, dx = s - 3 * dy;
      float h0, h1;
      if (it == 0) {
        h0 = al0[s] * a0[s] + be0[s];
        h1 = al1[s] * a1[s] + be1[s];
      } else {
        float p0 = be0[s] * cb[s] + be1[s] * sb[s];
        float p1 = be1[s] * cb[s] - be0[s] * sb[s];
        float g = gmv[s];
        h0 = al0[s] * (a0[s] + (1.f - g) * p0) + g * be0[s];
        h1 = al1[s] * (a1[s] + (1.f - g) * p1) + g * be1[s];
      }
      float2 hw; hw.x = h0; hw.y = h1;
      HS[cur ^ 1][(3 * bh + dy + 1) * 51 + (3 * bw + dx + 1)] = hw;
      if (it < 11) {
        float nb0 = be0[s] * cb[s] - be1[s] * sb[s];
        float nb1 = be0[s] * sb[s] + be1[s] * cb[s];
        be0[s] = nb0; be1[s] = nb1;
      }
    }
    __syncthreads();
    cur ^= 1;
  }

  ushort_t* outRow0 = HgBf + (size_t)(r * 64 + n0) * PTOT + pbase;
  ushort_t* outRow1 = HgBf + (size_t)(r * 64 + n1) * PTOT + pbase;
#pragma unroll
  for (int s = 0; s < 9; ++s) {
    int dy = s / 3, dx = s - 3 * dy;
    int i = (3 * bh + dy) * 48 + 3 * bw + dx;
    float c2 = cb[s] * cb[s] - sb[s] * sb[s], s2 = 2.f * cb[s] * sb[s];
    float c4 = c2 * c2 - s2 * s2,             s4 = 2.f * c2 * s2;
    float c8 = c4 * c4 - s4 * s4,             s8 = 2.f * c4 * s4;
    float c12 = c8 * c4 - s8 * s4,            s12 = c8 * s4 + s8 * c4;
    float C0 = bf2f(rowC0[i]), C1 = bf2f(rowC1[i]);
    float cr0 = C0 * c12 - C1 * s12;
    float cr1 = C0 * s12 + C1 * c12;
    float2 hv = HS[cur][(3 * bh + dy + 1) * 51 + (3 * bw + dx + 1)];
    outRow0[i] = f2bf(cr0 * hv.x);
    outRow1[i] = f2bf(cr1 * hv.y);
  }
}

// ---------------------------------------------------------------------------
// transpose: HgBf [k][p] bf16 -> Hbf [p][k] bf16 (f32 64x65 LDS tile).
// ---------------------------------------------------------------------------
__global__ __launch_bounds__(256) void transpose_cvt(
    const ushort_t* __restrict__ HgBf, ushort_t* __restrict__ Hbf) {
  __shared__ float T[64][65];
  const int tid = threadIdx.x;
  const int p0 = blockIdx.x * 64;
  const int k0 = blockIdx.y * 64;
  {
    int row = tid >> 2, q = tid & 3;
    const ushort_t* src = &HgBf[(size_t)(k0 + row) * PTOT + p0 + q * 16];
    uint4 u0 = *(const uint4*)src;
    uint4 u1 = *(const uint4*)(src + 8);
    const uint_t* up = (const uint_t*)&u0;
#pragma unroll
    for (int t = 0; t < 4; ++t) {
      T[row][q * 16 + 2 * t]     = bf2f((ushort_t)(up[t] & 0xffffu));
      T[row][q * 16 + 2 * t + 1] = bf2f((ushort_t)(up[t] >> 16));
    }
    const uint_t* vp = (const uint_t*)&u1;
#pragma unroll
    for (int t = 0; t < 4; ++t) {
      T[row][q * 16 + 8 + 2 * t]     = bf2f((ushort_t)(vp[t] & 0xffffu));
      T[row][q * 16 + 8 + 2 * t + 1] = bf2f((ushort_t)(vp[t] >> 16));
    }
  }
  __syncthreads();
  {
    int pr = tid >> 2, kq = tid & 3;
    uint_t Hw[8];
#pragma unroll
    for (int q = 0; q < 8; ++q)
      Hw[q] = cvt2_hi(T[kq * 16 + 2 * q][pr], T[kq * 16 + 2 * q + 1][pr]);
    size_t off = (size_t)(p0 + pr) * 256 + k0 + kq * 16;
    *(uint4*)&Hbf[off]     = make_uint4(Hw[0], Hw[1], Hw[2], Hw[3]);
    *(uint4*)&Hbf[off + 8] = make_uint4(Hw[4], Hw[5], Hw[6], Hw[7]);
  }
}

// ---------------------------------------------------------------------------
// GEMM C: BK=64 (4 phases of K=256), pure glds both operands, 32KB/buf,
// 64KB total -> 2 blocks/CU; 8-slot row map g = sp^(row&7). T5 setprio.
// ---------------------------------------------------------------------------
__global__ __launch_bounds__(512, 4) void gemm_out_glds(
    const ushort_t* __restrict__ Hbf, const ushort_t* __restrict__ WoT,
    const float* __restrict__ b_out, float* __restrict__ out) {
  __shared__ ushort_t As[2][8192];   // Hg tiles   (16 KB each)
  __shared__ ushort_t Bs[2][8192];   // W_out^T    (16 KB each)
  const int tid = threadIdx.x;
  const int lane = tid & 63, wv = tid >> 6;
  const int wr = wv >> 2, wc = wv & 3;
  const int lk = lane >> 4, lm = lane & 15;
  int lin = blockIdx.x;                    // 0..1727, 1728 = 8*216
  int id2 = (lin & 7) * 216 + (lin >> 3);
  const int jblk = id2 % 6, pblk = id2 / 6;
  const int j0 = jblk * 128, p0 = pblk * 128;

  f32x4 acc[4][2];
#pragma unroll
  for (int i = 0; i < 4; ++i)
#pragma unroll
    for (int j = 0; j < 2; ++j) acc[i][j] = (f32x4)0.f;

  auto stage = [&](int buf, int ph) {
    const int k0 = ph * 64;
#pragma unroll
    for (int j = 0; j < 2; ++j) {
      int mb = __builtin_amdgcn_readfirstlane(j * 512 + wv * 64);
      int m = mb + lane;
      int row = m >> 3, sp = m & 7;
      int g = sp ^ (row & 7);
      glds16(&Hbf[(size_t)(p0 + row) * 256 + k0 + g * 8],
             (void*)&As[buf][mb * 8]);
    }
#pragma unroll
    for (int j = 0; j < 2; ++j) {
      int mb = __builtin_amdgcn_readfirstlane(j * 512 + wv * 64);
      int m = mb + lane;
      int row = m >> 3, sp = m & 7;
      int g = sp ^ (row & 7);
      glds16(&WoT[(size_t)(j0 + row) * 256 + k0 + g * 8],
             (void*)&Bs[buf][mb * 8]);
    }
  };

  stage(0, 0);
  __syncthreads();

  for (int ph = 0; ph < 4; ++ph) {
    const int cur = ph & 1;
    if (ph + 1 < 4) stage(cur ^ 1, ph + 1);
    __builtin_amdgcn_s_setprio(1);
#pragma unroll
    for (int s = 0; s < 2; ++s) {
      bfx8 ah[4], bh[2];
#pragma unroll
      for (int f = 0; f < 4; ++f) {
        int ra = wr * 64 + f * 16 + lm;
        int slot = (s * 4 + lk) ^ (ra & 7);
        ah[f] = *(const bfx8*)&As[cur][(ra * 8 + slot) * 8];
      }
#pragma unroll
      for (int n = 0; n < 2; ++n) {
        int rb = wc * 32 + n * 16 + lm;
        int slot = (s * 4 + lk) ^ (rb & 7);
        bh[n] = *(const bfx8*)&Bs[cur][(rb * 8 + slot) * 8];
      }
#pragma unroll
      for (int i = 0; i < 4; ++i)
#pragma unroll
        for (int j = 0; j < 2; ++j)
          acc[i][j] = MFMA_BF16(ah[i], bh[j], acc[i][j]);
    }
    __builtin_amdgcn_s_setprio(0);
    __syncthreads();
  }

  float bo[2];
#pragma unroll
  for (int jj = 0; jj < 2; ++jj) bo[jj] = b_out[j0 + wc * 32 + jj * 16 + lm];
#pragma unroll
  for (int i = 0; i < 4; ++i) {
#pragma unroll
    for (int r = 0; r < 4; ++r) {
      int p = p0 + wr * 64 + i * 16 + lk * 4 + r;
      size_t rowoff = (size_t)p * DIM;
#pragma unroll
      for (int jj = 0; jj < 2; ++jj) {
        out[rowoff + j0 + wc * 32 + jj * 16 + lm] =
            siluf_(acc[i][jj][r] + bo[jj]);
      }
    }
  }
}

// ---------------------------------------------------------------------------
extern "C" void kernel_launch(void* const* d_in, const int* in_sizes, int n_in,
                              void* d_out, int out_size, void* d_ws, size_t ws_size,
                              hipStream_t stream) {
  const float* x      = (const float*)d_in[0];
  const float* W_B    = (const float*)d_in[1];
  const float* b_B    = (const float*)d_in[2];
  const float* W_C    = (const float*)d_in[3];
  const float* b_C    = (const float*)d_in[4];
  const float* W_X    = (const float*)d_in[5];
  const float* b_X    = (const float*)d_in[6];
  const float* W_dec  = (const float*)d_in[7];
  const float* b_dec  = (const float*)d_in[8];
  const float* W_th   = (const float*)d_in[9];
  const float* b_th   = (const float*)d_in[10];
  const float* W_lam  = (const float*)d_in[11];
  const float* b_lam  = (const float*)d_in[12];
  const float* B_bias = (const float*)d_in[13];
  const float* C_bias = (const float*)d_in[14];
  const float* conv_w = (const float*)d_in[15];
  const float* conv_b = (const float*)d_in[16];
  const float* W_out  = (const float*)d_in[17];
  const float* b_out  = (const float*)d_in[18];
  float* out = (float*)d_out;

  // workspace layout (~93 MB):
  //  weights 2.4 | projBC bf16 37.75 | projS f32 15.3 | HgBf 18.9 | Hbf 18.9
  ushort_t* WhiT   = (ushort_t*)d_ws;                     // 640*768
  ushort_t* WloT   = WhiT + (size_t)NCOLS * DIM;
  ushort_t* WoT    = WloT + (size_t)NCOLS * DIM;          // 768*256
  float* bias_all  = (float*)(WoT + (size_t)DIM * 256);   // 640
  ushort_t* projBC = (ushort_t*)(bias_all + NCOLS);       // 512*36864 bf16
  float* projS     = (float*)(projBC + (size_t)512 * PTOT);  // 104*36864 f32
  ushort_t* HgBf   = (ushort_t*)(projS + (size_t)104 * PTOT); // 256*36864 bf16
  ushort_t* Hbf    = HgBf + (size_t)256 * PTOT;           // 36864*256 bf16

  const int pack_elems = NCOLS * DIM + DIM * 256;
  pack_kernel<<<(pack_elems + 255) / 256, 256, 0, stream>>>(
      W_B, W_C, W_dec, W_th, W_X, W_lam,
      b_B, b_C, b_dec, b_th, b_X, b_lam, B_bias, C_bias, W_out,
      WhiT, WloT, WoT, bias_all);

  gemm_proj_fused<<<dim3(1440), 512, 0, stream>>>(
      x, WhiT, WloT, bias_all, projBC, projS);

  iter_kernel<<<dim3(32, 4, 16), 256, 0, stream>>>(
      projBC, projS, conv_w, conv_b, HgBf);

  transpose_cvt<<<dim3(PTOT / 64, 4), 256, 0, stream>>>(HgBf, Hbf);

  gemm_out_glds<<<dim3(6 * NPBLK), 512, 0, stream>>>(
      Hbf, WoT, b_out, out);
}

// Round 24
// 214.158 us; speedup vs baseline: 1.0281x; 1.0281x over previous
//
#include <hip/hip_runtime.h>
#include <hip/hip_bf16.h>
#include <math.h>

// Problem constants
#define PTOT 36864          // Bsz*Hs*Ws = 16*48*48
#define DIM 768
#define NCOLS 640           // packed projection columns (613 used, padded)
#define IMG 2304            // 48*48
#define KSTEPS 24           // 768/32
#define NPBLK 288           // PTOT/128

typedef unsigned short ushort_t;
typedef unsigned int uint_t;
typedef __attribute__((ext_vector_type(8))) short bfx8;
typedef __attribute__((ext_vector_type(4))) float f32x4;

#define MFMA_BF16(a, b, c) __builtin_amdgcn_mfma_f32_16x16x32_bf16((a), (b), (c), 0, 0, 0)

// barrier that does NOT drain vmcnt (glds completion is enforced per-wave via
// register dependencies BEFORE reaching this) — only ds ops + barrier.
#define LGKM_BARRIER() do {                               \
    asm volatile("s_waitcnt lgkmcnt(0)" ::: "memory");    \
    __builtin_amdgcn_s_barrier();                         \
    __builtin_amdgcn_sched_barrier(0);                    \
  } while (0)

__device__ __forceinline__ float sigmoidf_(float v) { return 1.f / (1.f + __expf(-v)); }
__device__ __forceinline__ float siluf_(float v)    { return v   / (1.f + __expf(-v)); }
__device__ __forceinline__ float rfl(float v) {
  return __int_as_float(__builtin_amdgcn_readfirstlane(__float_as_int(v)));
}
__device__ __forceinline__ float bf2f(ushort_t h) {
  return __uint_as_float(((uint_t)h) << 16);
}

// async global->LDS, 16B per lane; LDS dest = wave-uniform base + lane*16
typedef __attribute__((address_space(3))) unsigned int lds_uint;
typedef __attribute__((address_space(1))) const unsigned int g_uint;
__device__ __forceinline__ void glds16(const void* gsrc, void* ldst) {
  __builtin_amdgcn_global_load_lds((g_uint*)gsrc, (lds_uint*)ldst, 16, 0, 0);
}

// split a pair of f32 into packed bf16 hi word + bf16 lo word (cvt_pk-based)
__device__ __forceinline__ void split2(float a, float b, uint_t& hw, uint_t& lw) {
  __hip_bfloat162 hh = __float22bfloat162_rn(make_float2(a, b));
  uint_t hu; __builtin_memcpy(&hu, &hh, 4);
  float ha = __uint_as_float(hu << 16);
  float hb = __uint_as_float(hu & 0xffff0000u);
  __hip_bfloat162 ll = __float22bfloat162_rn(make_float2(a - ha, b - hb));
  uint_t lu; __builtin_memcpy(&lu, &ll, 4);
  hw = hu; lw = lu;
}
__device__ __forceinline__ uint_t cvt2_hi(float a, float b) {
  __hip_bfloat162 hh = __float22bfloat162_rn(make_float2(a, b));
  uint_t hu; __builtin_memcpy(&hu, &hh, 4);
  return hu;
}
__device__ __forceinline__ ushort_t f2bf(float a) {
  return (ushort_t)(cvt2_hi(a, 0.f) & 0xffffu);
}
__device__ __forceinline__ void split8_fast(const float* f, uint4& hi, uint4& lo) {
  uint_t* Hp = (uint_t*)&hi;
  uint_t* Lp = (uint_t*)&lo;
#pragma unroll
  for (int q = 0; q < 4; ++q) split2(f[2 * q], f[2 * q + 1], Hp[q], Lp[q]);
}
__device__ __forceinline__ void cvt8_hi(const float* f, uint4& hi) {
  uint_t* Hp = (uint_t*)&hi;
#pragma unroll
  for (int q = 0; q < 4; ++q) Hp[q] = cvt2_hi(f[2 * q], f[2 * q + 1]);
}

// ---------------------------------------------------------------------------
// pack: projection weights -> split-bf16 [c][k]; W_out^T -> plain bf16 [j][k];
// fused bias.
// ---------------------------------------------------------------------------
__global__ void pack_kernel(
    const float* __restrict__ W_B, const float* __restrict__ W_C,
    const float* __restrict__ W_dec, const float* __restrict__ W_th,
    const float* __restrict__ W_X, const float* __restrict__ W_lam,
    const float* __restrict__ b_B, const float* __restrict__ b_C,
    const float* __restrict__ b_dec, const float* __restrict__ b_th,
    const float* __restrict__ b_X, const float* __restrict__ b_lam,
    const float* __restrict__ B_bias, const float* __restrict__ C_bias,
    const float* __restrict__ W_out,
    ushort_t* __restrict__ WhiT, ushort_t* __restrict__ WloT,
    ushort_t* __restrict__ WoT, float* __restrict__ bias_all) {
  int idx = blockIdx.x * 256 + threadIdx.x;
  const int NW = NCOLS * DIM;          // 491520
  const int NWO = DIM * 256;           // 196608
  if (idx < NW) {
    int c = idx / DIM, k = idx - c * DIM;
    float v;
    if      (c < 256) v = W_B[k * 256 + c];
    else if (c < 512) v = W_C[k * 256 + (c - 256)];
    else if (c < 576) v = W_dec[k * 64 + (c - 512)];
    else if (c < 608) v = W_th[k * 32 + (c - 576)];
    else if (c < 612) v = W_X[k * 4 + (c - 608)];
    else if (c == 612) v = W_lam[k];
    else v = 0.f;
    uint_t hw, lw;
    split2(v, 0.f, hw, lw);
    WhiT[idx] = (ushort_t)(hw & 0xffffu);
    WloT[idx] = (ushort_t)(lw & 0xffffu);
  } else if (idx < NW + NWO) {
    int t = idx - NW;
    int j = t / 256, k = t - j * 256;
    WoT[t] = f2bf(W_out[k * DIM + j]);
  }
  if (idx < NCOLS) {
    int c = idx;
    float v;
    if      (c < 256) v = b_B[c] + B_bias[c];
    else if (c < 512) v = b_C[c - 256] + C_bias[c - 256];
    else if (c < 576) v = b_dec[c - 512];
    else if (c < 608) v = b_th[c - 576];
    else if (c < 612) v = b_X[c - 608];
    else if (c == 612) v = b_lam[0];
    else v = 0.f;
    bias_all[c] = v;
  }
}

// ---------------------------------------------------------------------------
// FUSED projection GEMM: one dispatch, 1440 blocks of 512 threads.
//   blocks [0,1152): LIGHT path (c 0-511, B/C), BK=64, async schedule:
//     W TRIPLE-buffered glds (16KB each, staged 2 phases ahead); x reg-staged
//     bf16 double-buffered (16KB each). Barriers are lgkm-only: each wave's
//     glds completion is enforced by its writeX register wait ONE PHASE EARLY
//     (loadX(ph+1) is issued after stageW(ph+1), so waiting its regs drains
//     stageW(ph+1) with a full phase of slack). No vmcnt at barriers.
//   blocks [1152,1440): HEAVY path (c 512-612), BK=32 (r12 structure,
//     __syncthreads): W hi+lo glds + x f32 glds, split-bf16 3-MFMA.
// LDS: light 3*16 + 2*16 = 80 KB; heavy 2*32 = 64 KB; union 80 KB -> 2/CU.
// ---------------------------------------------------------------------------
__global__ __launch_bounds__(512, 4) void gemm_proj_fused(
    const float* __restrict__ x, const ushort_t* __restrict__ WhiT,
    const ushort_t* __restrict__ WloT, const float* __restrict__ biasall,
    ushort_t* __restrict__ projBC, float* __restrict__ projS) {
  __shared__ ushort_t S[40960];   // 80 KB union
  const int tid = threadIdx.x;
  const int lane = tid & 63, wv = tid >> 6;   // 8 waves
  const int wr = wv >> 2, wc = wv & 3;        // 64c x 32p per wave
  const int lk = lane >> 4, lm = lane & 15;

  f32x4 acc[4][2];
#pragma unroll
  for (int i = 0; i < 4; ++i)
#pragma unroll
    for (int j = 0; j < 2; ++j) acc[i][j] = (f32x4)0.f;

  if (blockIdx.x < 1152) {
    // ------------------- LIGHT PATH (BK = 64, async) --------------------
    int lin = blockIdx.x;                  // 0..1151, 1152 = 8*144
    int id2 = (lin & 7) * 144 + (lin >> 3);
    const int cblk = id2 & 3, pblk = id2 >> 2;
    const int c0 = cblk * 128, p0 = pblk * 128;

    const int r0 = tid >> 3,         s0 = tid & 7,         g0 = s0 ^ (r0 & 7);
    const int r1 = (tid + 512) >> 3, s1 = (tid + 512) & 7, g1 = s1 ^ (r1 & 7);
    const float* xsrc0 = x + (size_t)(p0 + r0) * DIM + g0 * 8;
    const float* xsrc1 = x + (size_t)(p0 + r1) * DIM + g1 * 8;

    float4 xr[4];   // 16 VGPR prefetch

    // W buffers: base wb*8192 elems (wb 0..2); X buffers: 24576 + xb*8192.
    auto stageW = [&](int wb, int ph) {
      const int k0 = ph * 64;
#pragma unroll
      for (int j = 0; j < 2; ++j) {
        int mb = __builtin_amdgcn_readfirstlane(j * 512 + wv * 64);
        int m = mb + lane;
        int row = m >> 3, sp = m & 7;
        int g = sp ^ (row & 7);
        glds16(&WhiT[(size_t)(c0 + row) * DIM + k0 + g * 8],
               (void*)&S[wb * 8192 + mb * 8]);
      }
    };
    auto loadX = [&](int ph) {
      const float* q0 = xsrc0 + ph * 64;
      xr[0] = *(const float4*)q0;
      xr[1] = *(const float4*)(q0 + 4);
      const float* q1 = xsrc1 + ph * 64;
      xr[2] = *(const float4*)q1;
      xr[3] = *(const float4*)(q1 + 4);
    };
    auto writeX = [&](int xb) {
      float fv[8];
      uint4 hv;
      *(float4*)&fv[0] = xr[0]; *(float4*)&fv[4] = xr[1];
      cvt8_hi(fv, hv);
      *(uint4*)&S[24576 + xb * 8192 + (size_t)tid * 8] = hv;
      *(float4*)&fv[0] = xr[2]; *(float4*)&fv[4] = xr[3];
      cvt8_hi(fv, hv);
      *(uint4*)&S[24576 + xb * 8192 + (size_t)(tid + 512) * 8] = hv;
    };

    // prologue: issue order matters for the reg-dependency drains.
    stageW(0, 0);       // vmem
    loadX(0);           // vmem (after stageW(0))
    stageW(1, 1);       // vmem (after loadX(0))
    writeX(0);          // waits loadX(0) regs -> drains stageW(0)
    loadX(1);           // for phase 1 (after stageW(1))
    LGKM_BARRIER();     // publish X[0]; W(0) already drained above

    for (int ph = 0; ph < 12; ++ph) {
      const int wb = ph % 3, xb = ph & 1;
      if (ph + 2 < 12) stageW((ph + 2) % 3, ph + 2);
      if (ph + 1 < 12) writeX(xb ^ 1);   // waits loadX(ph+1) -> drains stageW(ph+1)
      if (ph + 2 < 12) loadX(ph + 2);
#pragma unroll
      for (int s = 0; s < 2; ++s) {
        bfx8 ah[4];
#pragma unroll
        for (int f = 0; f < 4; ++f) {
          int row = wr * 64 + f * 16 + lm;
          int slot = (s * 4 + lk) ^ (row & 7);
          ah[f] = *(const bfx8*)&S[wb * 8192 + (row * 8 + slot) * 8];
        }
        bfx8 bh[2];
#pragma unroll
        for (int n = 0; n < 2; ++n) {
          int row = wc * 32 + n * 16 + lm;
          int slot = (s * 4 + lk) ^ (row & 7);
          bh[n] = *(const bfx8*)&S[24576 + xb * 8192 + (row * 8 + slot) * 8];
        }
#pragma unroll
        for (int i = 0; i < 4; ++i)
#pragma unroll
          for (int j = 0; j < 2; ++j)
            acc[i][j] = MFMA_BF16(ah[i], bh[j], acc[i][j]);
      }
      LGKM_BARRIER();   // end of phase: publish writeX(ph+1); W(ph+1) drained
    }

#pragma unroll
    for (int i = 0; i < 4; ++i) {
#pragma unroll
      for (int r = 0; r < 4; ++r) {
        int c = c0 + wr * 64 + i * 16 + lk * 4 + r;
        float bia = biasall[c];
#pragma unroll
        for (int j = 0; j < 2; ++j) {
          float z = siluf_(acc[i][j][r] + bia);
          projBC[(size_t)c * PTOT + p0 + wc * 32 + j * 16 + lm] = f2bf(z);
        }
      }
    }
  } else {
    // ----------------------- HEAVY PATH (r12) ---------------------------
    int lin = blockIdx.x - 1152;           // 0..287, 288 = 8*36
    int id2 = (lin & 7) * 36 + (lin >> 3);
    const int pblk = id2;
    const int c0 = 512, p0 = pblk * 128;

    auto stage = [&](int buf, int kidx) {
      const int k0 = kidx * 32;
      {
        int mb = __builtin_amdgcn_readfirstlane(wv * 64);
        int m = mb + lane;
        int row = m >> 2, sp = m & 3;
        int g = sp ^ ((row >> 1) & 3);
        glds16(&WhiT[(size_t)(c0 + row) * DIM + k0 + g * 8],
               (void*)&S[buf * 16384 + mb * 8]);
      }
      {
        int mb = __builtin_amdgcn_readfirstlane(wv * 64);
        int m = mb + lane;
        int row = m >> 2, sp = m & 3;
        int g = sp ^ ((row >> 1) & 3);
        glds16(&WloT[(size_t)(c0 + row) * DIM + k0 + g * 8],
               (void*)&S[buf * 16384 + 4096 + mb * 8]);
      }
      float* Xf = (float*)&S[buf * 16384 + 8192];
#pragma unroll
      for (int j = 0; j < 2; ++j) {
        int mb = __builtin_amdgcn_readfirstlane(j * 512 + wv * 64);
        int m = mb + lane;
        int row = m >> 3, sp = m & 7;
        int g = sp ^ (row & 7);
        glds16(&x[(size_t)(p0 + row) * DIM + k0 + g * 4],
               (void*)&Xf[mb * 4]);
      }
    };

    stage(0, 0);
    __syncthreads();

    for (int kidx = 0; kidx < KSTEPS; ++kidx) {
      const int cur = kidx & 1;
      if (kidx + 1 < KSTEPS) stage(cur ^ 1, kidx + 1);

      bfx8 ah[4], al[4];
#pragma unroll
      for (int f = 0; f < 4; ++f) {
        int row = wr * 64 + f * 16 + lm;
        int sp = lk ^ ((row >> 1) & 3);
        int idx = (row * 4 + sp) * 8;
        ah[f] = *(const bfx8*)&S[cur * 16384 + idx];
        al[f] = *(const bfx8*)&S[cur * 16384 + 4096 + idx];
      }
      const float* Xf = (const float*)&S[cur * 16384 + 8192];
      bfx8 bh[2], bl[2];
#pragma unroll
      for (int n = 0; n < 2; ++n) {
        int row = wc * 32 + n * 16 + lm;
        int sp0 = (2 * lk)     ^ (row & 7);
        int sp1 = (2 * lk + 1) ^ (row & 7);
        float fv[8];
        *(float4*)&fv[0] = *(const float4*)&Xf[(row * 8 + sp0) * 4];
        *(float4*)&fv[4] = *(const float4*)&Xf[(row * 8 + sp1) * 4];
        uint4 hv, lv;
        split8_fast(fv, hv, lv);
        bh[n] = *(bfx8*)&hv;
        bl[n] = *(bfx8*)&lv;
      }
#pragma unroll
      for (int i = 0; i < 4; ++i)
#pragma unroll
        for (int j = 0; j < 2; ++j) {
          acc[i][j] = MFMA_BF16(ah[i], bh[j], acc[i][j]);
          acc[i][j] = MFMA_BF16(al[i], bh[j], acc[i][j]);
          acc[i][j] = MFMA_BF16(ah[i], bl[j], acc[i][j]);
        }
      __syncthreads();
    }

#pragma unroll
    for (int i = 0; i < 4; ++i) {
#pragma unroll
      for (int r = 0; r < 4; ++r) {
        int c = c0 + wr * 64 + i * 16 + lk * 4 + r;
        if (c >= 613) continue;
        float bia = biasall[c];
        int rowo = c - 512;
        bool do_silu = (c >= 608 && c < 612);
        bool do_sig  = (c < 576) || (c == 612);
#pragma unroll
        for (int j = 0; j < 2; ++j) {
          float z = acc[i][j][r] + bia;
          if (do_silu) z = siluf_(z);
          else if (do_sig) z = sigmoidf_(z);
          projS[(size_t)rowo * PTOT + p0 + wc * 32 + j * 16 + lm] = z;
        }
      }
    }
  }
}

// ---------------------------------------------------------------------------
// Iteration kernel: one block per (n-pair, r, batch), 12 iterations fused.
// ---------------------------------------------------------------------------
__global__ __launch_bounds__(256) void iter_kernel(
    const ushort_t* __restrict__ projBC, const float* __restrict__ projS,
    const float* __restrict__ conv_w, const float* __restrict__ conv_b,
    ushort_t* __restrict__ HgBf) {
  const int n2 = blockIdx.x;   // channel pair 0..31
  const int r  = blockIdx.y;   // 0..3
  const int b  = blockIdx.z;   // 0..15
  const int n0 = 2 * n2, n1 = n0 + 1;
  const int tid = threadIdx.x;
  const int bh = tid >> 4, bw = tid & 15;   // 3x3 strip coords
  const int pbase = b * IMG;

  __shared__ float2 HS[2][50 * 51];   // [buf][(h+1)*51 + (w+1)], zero halo

  float w0[9], w1[9];
#pragma unroll
  for (int t = 0; t < 9; ++t) {
    w0[t] = rfl(conv_w[t * 64 + n0]);
    w1[t] = rfl(conv_w[t * 64 + n1]);
  }
  const float cvb0 = rfl(conv_b[n0]), cvb1 = rfl(conv_b[n1]);

  {
    float4 zz = {0.f, 0.f, 0.f, 0.f};
    float4* z = (float4*)&HS[0][0];
#pragma unroll
    for (int u = 0; u < 10; ++u) {
      int q = tid + 256 * u;
      if (q < 2550) z[q] = zz;
    }
  }

  const ushort_t* rowB0 = projBC + (size_t)(n0 * 4 + r) * PTOT + pbase;
  const ushort_t* rowB1 = projBC + (size_t)(n1 * 4 + r) * PTOT + pbase;
  const ushort_t* rowC0 = projBC + (size_t)(256 + n0 * 4 + r) * PTOT + pbase;
  const ushort_t* rowC1 = projBC + (size_t)(256 + n1 * 4 + r) * PTOT + pbase;
  const float* rowA0 = projS + (size_t)n0 * PTOT + pbase;          // alpha
  const float* rowA1 = projS + (size_t)n1 * PTOT + pbase;
  const float* rowTh = projS + (size_t)(64 + n2) * PTOT + pbase;   // theta
  const float* rowXv = projS + (size_t)(96 + r) * PTOT + pbase;    // X
  const float* rowGm = projS + (size_t)100 * PTOT + pbase;         // gamma

  float be0[9], be1[9], cb[9], sb[9], al0[9], al1[9], gmv[9];
#pragma unroll
  for (int s = 0; s < 9; ++s) {
    int dy = s / 3, dx = s - 3 * dy;
    int i = (3 * bh + dy) * 48 + 3 * bw + dx;
    float sn, cn;
    __sincosf(rowTh[i], &sn, &cn);
    cb[s] = cn; sb[s] = sn;
    float B0 = bf2f(rowB0[i]), B1 = bf2f(rowB1[i]), X = rowXv[i];
    be0[s] = (B0 * cn - B1 * sn) * X;   // inj at angle theta (iteration 0)
    be1[s] = (B0 * sn + B1 * cn) * X;
    al0[s] = rowA0[i]; al1[s] = rowA1[i];
    gmv[s] = rowGm[i];
  }
  __syncthreads();

  int cur = 0;
  for (int it = 0; it < 12; ++it) {
    float a0[9], a1[9];
#pragma unroll
    for (int s = 0; s < 9; ++s) { a0[s] = cvb0; a1[s] = cvb1; }
#pragma unroll
    for (int yy = 0; yy < 5; ++yy) {
      float2 row[5];
#pragma unroll
      for (int xx = 0; xx < 5; ++xx)
        row[xx] = HS[cur][(3 * bh + yy) * 51 + 3 * bw + xx];
#pragma unroll
      for (int dy = 0; dy < 3; ++dy) {
        int ty = yy - dy;
        if (ty < 0 || ty > 2) continue;
#pragma unroll
        for (int dx = 0; dx < 3; ++dx)
#pragma unroll
          for (int tx = 0; tx < 3; ++tx) {
            a0[dy * 3 + dx] += row[dx + tx].x * w0[ty * 3 + tx];
            a1[dy * 3 + dx] += row[dx + tx].y * w1[ty * 3 + tx];
          }
      }
    }
#pragma unroll
    for (int s = 0; s < 9; ++s) {
      int dy = s / 3, dx = s - 3 * dy;
      float h0, h1;
      if (it == 0) {
        h0 = al0[s] * a0[s] + be0[s];
        h1 = al1[s] * a1[s] + be1[s];
      } else {
        float p0 = be0[s] * cb[s] + be1[s] * sb[s];
        float p1 = be1[s] * cb[s] - be0[s] * sb[s];
        float g = gmv[s];
        h0 = al0[s] * (a0[s] + (1.f - g) * p0) + g * be0[s];
        h1 = al1[s] * (a1[s] + (1.f - g) * p1) + g * be1[s];
      }
      float2 hw; hw.x = h0; hw.y = h1;
      HS[cur ^ 1][(3 * bh + dy + 1) * 51 + (3 * bw + dx + 1)] = hw;
      if (it < 11) {
        float nb0 = be0[s] * cb[s] - be1[s] * sb[s];
        float nb1 = be0[s] * sb[s] + be1[s] * cb[s];
        be0[s] = nb0; be1[s] = nb1;
      }
    }
    __syncthreads();
    cur ^= 1;
  }

  ushort_t* outRow0 = HgBf + (size_t)(r * 64 + n0) * PTOT + pbase;
  ushort_t* outRow1 = HgBf + (size_t)(r * 64 + n1) * PTOT + pbase;
#pragma unroll
  for (int s = 0; s < 9; ++s) {
    int dy = s / 3, dx = s - 3 * dy;
    int i = (3 * bh + dy) * 48 + 3 * bw + dx;
    float c2 = cb[s] * cb[s] - sb[s] * sb[s], s2 = 2.f * cb[s] * sb[s];
    float c4 = c2 * c2 - s2 * s2,             s4 = 2.f * c2 * s2;
    float c8 = c4 * c4 - s4 * s4,             s8 = 2.f * c4 * s4;
    float c12 = c8 * c4 - s8 * s4,            s12 = c8 * s4 + s8 * c4;
    float C0 = bf2f(rowC0[i]), C1 = bf2f(rowC1[i]);
    float cr0 = C0 * c12 - C1 * s12;
    float cr1 = C0 * s12 + C1 * c12;
    float2 hv = HS[cur][(3 * bh + dy + 1) * 51 + (3 * bw + dx + 1)];
    outRow0[i] = f2bf(cr0 * hv.x);
    outRow1[i] = f2bf(cr1 * hv.y);
  }
}

// ---------------------------------------------------------------------------
// transpose: HgBf [k][p] bf16 -> Hbf [p][k] bf16 (f32 64x65 LDS tile).
// ---------------------------------------------------------------------------
__global__ __launch_bounds__(256) void transpose_cvt(
    const ushort_t* __restrict__ HgBf, ushort_t* __restrict__ Hbf) {
  __shared__ float T[64][65];
  const int tid = threadIdx.x;
  const int p0 = blockIdx.x * 64;
  const int k0 = blockIdx.y * 64;
  {
    int row = tid >> 2, q = tid & 3;
    const ushort_t* src = &HgBf[(size_t)(k0 + row) * PTOT + p0 + q * 16];
    uint4 u0 = *(const uint4*)src;
    uint4 u1 = *(const uint4*)(src + 8);
    const uint_t* up = (const uint_t*)&u0;
#pragma unroll
    for (int t = 0; t < 4; ++t) {
      T[row][q * 16 + 2 * t]     = bf2f((ushort_t)(up[t] & 0xffffu));
      T[row][q * 16 + 2 * t + 1] = bf2f((ushort_t)(up[t] >> 16));
    }
    const uint_t* vp = (const uint_t*)&u1;
#pragma unroll
    for (int t = 0; t < 4; ++t) {
      T[row][q * 16 + 8 + 2 * t]     = bf2f((ushort_t)(vp[t] & 0xffffu));
      T[row][q * 16 + 8 + 2 * t + 1] = bf2f((ushort_t)(vp[t] >> 16));
    }
  }
  __syncthreads();
  {
    int pr = tid >> 2, kq = tid & 3;
    uint_t Hw[8];
#pragma unroll
    for (int q = 0; q < 8; ++q)
      Hw[q] = cvt2_hi(T[kq * 16 + 2 * q][pr], T[kq * 16 + 2 * q + 1][pr]);
    size_t off = (size_t)(p0 + pr) * 256 + k0 + kq * 16;
    *(uint4*)&Hbf[off]     = make_uint4(Hw[0], Hw[1], Hw[2], Hw[3]);
    *(uint4*)&Hbf[off + 8] = make_uint4(Hw[4], Hw[5], Hw[6], Hw[7]);
  }
}

// ---------------------------------------------------------------------------
// GEMM C: BK=64 (4 phases of K=256), pure glds both operands, 32KB/buf,
// 64KB total -> 2 blocks/CU; 8-slot row map g = sp^(row&7).
// ---------------------------------------------------------------------------
__global__ __launch_bounds__(512, 4) void gemm_out_glds(
    const ushort_t* __restrict__ Hbf, const ushort_t* __restrict__ WoT,
    const float* __restrict__ b_out, float* __restrict__ out) {
  __shared__ ushort_t As[2][8192];   // Hg tiles   (16 KB each)
  __shared__ ushort_t Bs[2][8192];   // W_out^T    (16 KB each)
  const int tid = threadIdx.x;
  const int lane = tid & 63, wv = tid >> 6;
  const int wr = wv >> 2, wc = wv & 3;
  const int lk = lane >> 4, lm = lane & 15;
  int lin = blockIdx.x;                    // 0..1727, 1728 = 8*216
  int id2 = (lin & 7) * 216 + (lin >> 3);
  const int jblk = id2 % 6, pblk = id2 / 6;
  const int j0 = jblk * 128, p0 = pblk * 128;

  f32x4 acc[4][2];
#pragma unroll
  for (int i = 0; i < 4; ++i)
#pragma unroll
    for (int j = 0; j < 2; ++j) acc[i][j] = (f32x4)0.f;

  auto stage = [&](int buf, int ph) {
    const int k0 = ph * 64;
#pragma unroll
    for (int j = 0; j < 2; ++j) {
      int mb = __builtin_amdgcn_readfirstlane(j * 512 + wv * 64);
      int m = mb + lane;
      int row = m >> 3, sp = m & 7;
      int g = sp ^ (row & 7);
      glds16(&Hbf[(size_t)(p0 + row) * 256 + k0 + g * 8],
             (void*)&As[buf][mb * 8]);
    }
#pragma unroll
    for (int j = 0; j < 2; ++j) {
      int mb = __builtin_amdgcn_readfirstlane(j * 512 + wv * 64);
      int m = mb + lane;
      int row = m >> 3, sp = m & 7;
      int g = sp ^ (row & 7);
      glds16(&WoT[(size_t)(j0 + row) * 256 + k0 + g * 8],
             (void*)&Bs[buf][mb * 8]);
    }
  };

  stage(0, 0);
  __syncthreads();

  for (int ph = 0; ph < 4; ++ph) {
    const int cur = ph & 1;
    if (ph + 1 < 4) stage(cur ^ 1, ph + 1);
#pragma unroll
    for (int s = 0; s < 2; ++s) {
      bfx8 ah[4], bh[2];
#pragma unroll
      for (int f = 0; f < 4; ++f) {
        int ra = wr * 64 + f * 16 + lm;
        int slot = (s * 4 + lk) ^ (ra & 7);
        ah[f] = *(const bfx8*)&As[cur][(ra * 8 + slot) * 8];
      }
#pragma unroll
      for (int n = 0; n < 2; ++n) {
        int rb = wc * 32 + n * 16 + lm;
        int slot = (s * 4 + lk) ^ (rb & 7);
        bh[n] = *(const bfx8*)&Bs[cur][(rb * 8 + slot) * 8];
      }
#pragma unroll
      for (int i = 0; i < 4; ++i)
#pragma unroll
        for (int j = 0; j < 2; ++j)
          acc[i][j] = MFMA_BF16(ah[i], bh[j], acc[i][j]);
    }
    __syncthreads();
  }

  float bo[2];
#pragma unroll
  for (int jj = 0; jj < 2; ++jj) bo[jj] = b_out[j0 + wc * 32 + jj * 16 + lm];
#pragma unroll
  for (int i = 0; i < 4; ++i) {
#pragma unroll
    for (int r = 0; r < 4; ++r) {
      int p = p0 + wr * 64 + i * 16 + lk * 4 + r;
      size_t rowoff = (size_t)p * DIM;
#pragma unroll
      for (int jj = 0; jj < 2; ++jj) {
        out[rowoff + j0 + wc * 32 + jj * 16 + lm] =
            siluf_(acc[i][jj][r] + bo[jj]);
      }
    }
  }
}

// ---------------------------------------------------------------------------
extern "C" void kernel_launch(void* const* d_in, const int* in_sizes, int n_in,
                              void* d_out, int out_size, void* d_ws, size_t ws_size,
                              hipStream_t stream) {
  const float* x      = (const float*)d_in[0];
  const float* W_B    = (const float*)d_in[1];
  const float* b_B    = (const float*)d_in[2];
  const float* W_C    = (const float*)d_in[3];
  const float* b_C    = (const float*)d_in[4];
  const float* W_X    = (const float*)d_in[5];
  const float* b_X    = (const float*)d_in[6];
  const float* W_dec  = (const float*)d_in[7];
  const float* b_dec  = (const float*)d_in[8];
  const float* W_th   = (const float*)d_in[9];
  const float* b_th   = (const float*)d_in[10];
  const float* W_lam  = (const float*)d_in[11];
  const float* b_lam  = (const float*)d_in[12];
  const float* B_bias = (const float*)d_in[13];
  const float* C_bias = (const float*)d_in[14];
  const float* conv_w = (const float*)d_in[15];
  const float* conv_b = (const float*)d_in[16];
  const float* W_out  = (const float*)d_in[17];
  const float* b_out  = (const float*)d_in[18];
  float* out = (float*)d_out;

  // workspace layout (~93 MB):
  //  weights 2.4 | projBC bf16 37.75 | projS f32 15.3 | HgBf 18.9 | Hbf 18.9
  ushort_t* WhiT   = (ushort_t*)d_ws;                     // 640*768
  ushort_t* WloT   = WhiT + (size_t)NCOLS * DIM;
  ushort_t* WoT    = WloT + (size_t)NCOLS * DIM;          // 768*256
  float* bias_all  = (float*)(WoT + (size_t)DIM * 256);   // 640
  ushort_t* projBC = (ushort_t*)(bias_all + NCOLS);       // 512*36864 bf16
  float* projS     = (float*)(projBC + (size_t)512 * PTOT);  // 104*36864 f32
  ushort_t* HgBf   = (ushort_t*)(projS + (size_t)104 * PTOT); // 256*36864 bf16
  ushort_t* Hbf    = HgBf + (size_t)256 * PTOT;           // 36864*256 bf16

  const int pack_elems = NCOLS * DIM + DIM * 256;
  pack_kernel<<<(pack_elems + 255) / 256, 256, 0, stream>>>(
      W_B, W_C, W_dec, W_th, W_X, W_lam,
      b_B, b_C, b_dec, b_th, b_X, b_lam, B_bias, C_bias, W_out,
      WhiT, WloT, WoT, bias_all);

  gemm_proj_fused<<<dim3(1440), 512, 0, stream>>>(
      x, WhiT, WloT, bias_all, projBC, projS);

  iter_kernel<<<dim3(32, 4, 16), 256, 0, stream>>>(
      projBC, projS, conv_w, conv_b, HgBf);

  transpose_cvt<<<dim3(PTOT / 64, 4), 256, 0, stream>>>(HgBf, Hbf);

  gemm_out_glds<<<dim3(6 * NPBLK), 512, 0, stream>>>(
      Hbf, WoT, b_out, out);
}